// Round 1
// baseline (573.692 us; speedup 1.0000x reference)
//
#include <hip/hip_runtime.h>
#include <cmath>

#define NA 3

// ws layout:
//   sums:    double[16]        @ 0
//     [3]=excl_nb [4]=excl_conf [5]=excl_cnt
//     [6]=lx [7]=ly [8]=lw [9]=lh [10]=bce_obj [11]=conf_obj [12]=i50det [13]=i75det [14]=n_obj
//   ocell:   int[T]            @ 128
//   keyarr:  int[T]            @ 128 + 4T
//   partials double[nblk3*3]   @ 128 + 8T

__device__ __forceinline__ float sigf(float v){ return 1.0f/(1.0f + expf(-v)); }

__global__ __launch_bounds__(256) void k_targets(
    const float* __restrict__ targets, int T, int G, float stride,
    int* __restrict__ ocell, int* __restrict__ keyarr, double* __restrict__ sums)
{
  int t = blockIdx.x*256 + threadIdx.x;
  if (blockIdx.x == 0 && threadIdx.x < 16) sums[threadIdx.x] = 0.0;
  if (t >= T) return;
  const float* tr = targets + (size_t)t*6;
  int b = (int)tr[0];
  float gx = tr[2]*(float)G, gy = tr[3]*(float)G, gw = tr[4]*(float)G, gh = tr[5]*(float)G;
  float aw[NA] = {116.0f/stride, 156.0f/stride, 373.0f/stride};
  float ah[NA] = { 90.0f/stride, 198.0f/stride, 326.0f/stride};
  float best_iou = -1.0f; int best = 0; int bits = 0;
  #pragma unroll
  for (int a = 0; a < NA; ++a){
    float inter = fminf(aw[a], gw) * fminf(ah[a], gh);
    float uni   = aw[a]*ah[a] + gw*gh - inter;
    float iou   = inter / (uni + 1e-16f);
    if (iou > best_iou){ best_iou = iou; best = a; }
    if (iou > 0.5f) bits |= (1 << a);
  }
  bits |= (1 << best);
  int gi = (int)floorf(gx); gi = gi < 0 ? 0 : (gi > G-1 ? G-1 : gi);
  int gj = (int)floorf(gy); gj = gj < 0 ? 0 : (gj > G-1 ? G-1 : gj);
  int cellBJI = (b*G + gj)*G + gi;          // < 2^21
  ocell[t]  = cellBJI*4 + best;             // unique per (b,best,gj,gi)
  keyarr[t] = (cellBJI << 3) | bits;        // cell + exclusion anchor bits
}

__global__ __launch_bounds__(256) void k_sparse(
    const float* __restrict__ x, const float* __restrict__ targets,
    int T, int G, float stride,
    const int* __restrict__ ocell, const int* __restrict__ keyarr,
    double* __restrict__ sums)
{
  __shared__ int s_ocell[4096];
  __shared__ int s_key[4096];
  __shared__ double red[256];
  int tid = threadIdx.x;
  for (int i = tid; i < T && i < 4096; i += 256){ s_ocell[i] = ocell[i]; s_key[i] = keyarr[i]; }
  __syncthreads();

  int t = blockIdx.x*256 + tid;
  double v_enb=0, v_econf=0, v_ecnt=0;
  double v_lx=0, v_ly=0, v_lw=0, v_lh=0, v_bce=0, v_cobj=0, v_i50=0, v_i75=0, v_nobj=0;

  if (t < T){
    const float* tr = targets + (size_t)t*6;
    int b = (int)tr[0];
    float gx = tr[2]*(float)G, gy = tr[3]*(float)G, gw = tr[4]*(float)G, gh = tr[5]*(float)G;
    float aw[NA] = {116.0f/stride, 156.0f/stride, 373.0f/stride};
    float ah[NA] = { 90.0f/stride, 198.0f/stride, 326.0f/stride};
    int myo = s_ocell[t];
    int myk = s_key[t];
    int mycell = myk >> 3;
    int bits = myk & 7;
    int best = myo & 3;
    int gi = mycell % G;
    int gj = (mycell / G) % G;
    int GG = G*G;

    // --- last-target-wins owner check for the obj cell (numpy scatter semantics)
    bool owner = true;
    for (int u = t+1; u < T; ++u){
      if (s_ocell[u] == myo){ owner = false; break; }
    }

    if (owner){
      float awb = aw[best], ahb = ah[best];
      const float* xp = x + ((size_t)(b*(NA*5) + best*5))*GG + (size_t)gj*G + gi;
      float x0 = xp[0], x1 = xp[(size_t)GG], x2 = xp[(size_t)2*GG], x3 = xp[(size_t)3*GG], x4 = xp[(size_t)4*GG];
      float cx = sigf(x0), cy = sigf(x1), w = x2, h = x3, conf = sigf(x4);
      float tx = gx - (float)gi, ty = gy - (float)gj;
      float tw = logf(gw/awb + 1e-16f), th = logf(gh/ahb + 1e-16f);
      v_lx = (double)((cx-tx)*(cx-tx));
      v_ly = (double)((cy-ty)*(cy-ty));
      v_lw = (double)((w-tw)*(w-tw));
      v_lh = (double)((h-th)*(h-th));
      v_bce = (double)(-logf(conf + 1e-12f));
      v_cobj = (double)conf;
      // iou(pred box, target box), grid units
      float px = (float)gi + cx, py = (float)gj + cy;
      float pw = expf(w)*awb, ph = expf(h)*ahb;
      float iw = fminf(px + pw*0.5f, gx + gw*0.5f) - fmaxf(px - pw*0.5f, gx - gw*0.5f);
      float ih = fminf(py + ph*0.5f, gy + gh*0.5f) - fmaxf(py - ph*0.5f, gy - gh*0.5f);
      iw = fmaxf(iw, 0.0f); ih = fmaxf(ih, 0.0f);
      float inter = iw*ih;
      float iou = inter / (pw*ph + gw*gh - inter + 1e-16f);
      bool det = conf > 0.5f;
      v_i50 = (iou > 0.5f  && det) ? 1.0 : 0.0;
      v_i75 = (iou > 0.75f && det) ? 1.0 : 0.0;
      v_nobj = 1.0;
    }

    // --- exclusion (no_obj_mask zeros) counted once per distinct (b,a,gj,gi):
    // owner is the FIRST target claiming that cell+anchor
    int claimed = 0;
    for (int u = 0; u < t; ++u){
      int ku = s_key[u];
      if ((ku >> 3) == mycell){
        claimed |= (ku & bits);
        if ((claimed & bits) == bits) break;
      }
    }
    int mine = bits & ~claimed;
    #pragma unroll
    for (int a = 0; a < NA; ++a){
      if (mine & (1 << a)){
        float x4 = x[((size_t)(b*(NA*5) + a*5 + 4))*GG + (size_t)gj*G + gi];
        float conf = sigf(x4);
        v_enb  += (double)(-logf(1.0f - conf + 1e-12f));
        v_econf += (double)conf;
        v_ecnt += 1.0;
      }
    }
  }

  // block-reduce 12 doubles, atomicAdd to sums[3..14]
  double vals[12] = {v_enb, v_econf, v_ecnt, v_lx, v_ly, v_lw, v_lh, v_bce, v_cobj, v_i50, v_i75, v_nobj};
  for (int k = 0; k < 12; ++k){
    red[tid] = vals[k];
    __syncthreads();
    for (int s = 128; s > 0; s >>= 1){
      if (tid < s) red[tid] += red[tid + s];
      __syncthreads();
    }
    if (tid == 0) atomicAdd(&sums[3 + k], red[0]);
    __syncthreads();
  }
}

__global__ __launch_bounds__(256) void k_dense(
    const float* __restrict__ x, float* __restrict__ out,
    double* __restrict__ partials, int G, float stride, int total_quads)
{
  int i = blockIdx.x*256 + threadIdx.x;
  double nb = 0.0, cs = 0.0, c50 = 0.0;
  if (i < total_quads){
    int GG = G*G;
    int cell  = i*4;
    int gx    = cell % G;           // multiple of 4
    int row   = cell / G;
    int gy    = row % G;
    int plane = row / G;
    int a     = plane % NA;
    int b     = plane / NA;
    float aw_all[NA] = {116.0f/stride, 156.0f/stride, 373.0f/stride};
    float ah_all[NA] = { 90.0f/stride, 198.0f/stride, 326.0f/stride};
    float aw = aw_all[a], ah = ah_all[a];

    size_t base = ((size_t)(b*15 + a*5))*GG + (size_t)gy*G + gx;
    float4 v0 = *(const float4*)(x + base);
    float4 v1 = *(const float4*)(x + base + (size_t)GG);
    float4 v2 = *(const float4*)(x + base + (size_t)2*GG);
    float4 v3 = *(const float4*)(x + base + (size_t)3*GG);
    float4 v4 = *(const float4*)(x + base + (size_t)4*GG);
    const float* p0 = (const float*)&v0;
    const float* p1 = (const float*)&v1;
    const float* p2 = (const float*)&v2;
    const float* p3 = (const float*)&v3;
    const float* p4 = (const float*)&v4;

    float o[20];
    #pragma unroll
    for (int j = 0; j < 4; ++j){
      float cx   = 1.0f/(1.0f + expf(-p0[j]));
      float cy   = 1.0f/(1.0f + expf(-p1[j]));
      float pw   = expf(p2[j])*aw;
      float ph   = expf(p3[j])*ah;
      float conf = 1.0f/(1.0f + expf(-p4[j]));
      o[j*5+0] = ((float)(gx + j) + cx)*stride;
      o[j*5+1] = ((float)gy + cy)*stride;
      o[j*5+2] = pw*stride;
      o[j*5+3] = ph*stride;
      o[j*5+4] = conf;
      nb += (double)(-logf(1.0f - conf + 1e-12f));
      cs += (double)conf;
      c50 += (conf > 0.5f) ? 1.0 : 0.0;
    }
    float4* od = (float4*)(out + (size_t)cell*5);   // cell%4==0 -> 80B offset -> 16B aligned
    const float4* ov = (const float4*)o;
    #pragma unroll
    for (int j = 0; j < 5; ++j) od[j] = ov[j];
  }

  __shared__ double red[256];
  int tid = threadIdx.x;
  double vals[3] = {nb, cs, c50};
  #pragma unroll
  for (int k = 0; k < 3; ++k){
    red[tid] = vals[k];
    __syncthreads();
    for (int s = 128; s > 0; s >>= 1){
      if (tid < s) red[tid] += red[tid + s];
      __syncthreads();
    }
    if (tid == 0) partials[(size_t)blockIdx.x*3 + k] = red[0];
    __syncthreads();
  }
}

__global__ __launch_bounds__(256) void k_final(
    const double* __restrict__ sums, const double* __restrict__ partials,
    int nblk, float* __restrict__ tail, double total_cells)
{
  __shared__ double red[3*256];
  int tid = threadIdx.x;
  double nb = 0, cs = 0, c50 = 0;
  for (int i = tid; i < nblk; i += 256){
    nb  += partials[(size_t)i*3 + 0];
    cs  += partials[(size_t)i*3 + 1];
    c50 += partials[(size_t)i*3 + 2];
  }
  red[tid] = nb; red[256 + tid] = cs; red[512 + tid] = c50;
  __syncthreads();
  for (int s = 128; s > 0; s >>= 1){
    if (tid < s){
      red[tid]       += red[tid + s];
      red[256 + tid] += red[256 + tid + s];
      red[512 + tid] += red[512 + tid + s];
    }
    __syncthreads();
  }
  if (tid == 0){
    double nb_all = red[0], conf_all = red[256], c50_all = red[512];
    double enb = sums[3], econf = sums[4], ecnt = sums[5];
    double lx = sums[6], ly = sums[7], lw = sums[8], lh = sums[9];
    double bce = sums[10], cobj = sums[11], i50 = sums[12], i75 = sums[13], nobj = sums[14];

    double dObj = fmax(nobj, 1.0);
    double n_noobj = total_cells - ecnt;
    double dNo  = fmax(n_noobj, 1.0);

    double loss_x = lx/dObj, loss_y = ly/dObj, loss_w = lw/dObj, loss_h = lh/dObj;
    double loss_bbox = loss_x + loss_y + loss_w + loss_h;
    double loss_conf_obj   = bce/dObj;
    double loss_conf_noobj = (nb_all - enb)/dNo;
    double loss_conf  = 100.0*loss_conf_obj + 1.0*loss_conf_noobj;
    double loss_layer = loss_bbox + loss_conf;
    double conf_obj   = cobj/dObj;
    double conf_noobj = (conf_all - econf)/dNo;
    double precision  = i50/(c50_all + 1e-16);
    double recall50   = i50/(nobj + 1e-16);
    double recall75   = i75/(nobj + 1e-16);

    tail[0]  = (float)loss_layer;
    tail[1]  = (float)loss_x;
    tail[2]  = (float)loss_y;
    tail[3]  = (float)loss_w;
    tail[4]  = (float)loss_h;
    tail[5]  = (float)loss_bbox;
    tail[6]  = (float)loss_conf;
    tail[7]  = (float)loss_layer;
    tail[8]  = (float)conf_obj;
    tail[9]  = (float)conf_noobj;
    tail[10] = (float)precision;
    tail[11] = (float)recall50;
    tail[12] = (float)recall75;
  }
}

extern "C" void kernel_launch(void* const* d_in, const int* in_sizes, int n_in,
                              void* d_out, int out_size, void* d_ws, size_t ws_size,
                              hipStream_t stream) {
  const float* x       = (const float*)d_in[0];
  const float* targets = (const float*)d_in[1];
  float* out = (float*)d_out;

  const int B = 32;
  int GG = in_sizes[0] / (B * NA * 5);
  int G = (int)(sqrt((double)GG) + 0.5);
  int T = in_sizes[1] / 6;
  float stride = 2048.0f / (float)G;

  double* sums    = (double*)d_ws;
  int*    ocell   = (int*)((char*)d_ws + 128);
  int*    keyarr  = (int*)((char*)d_ws + 128 + (size_t)4*T);
  double* partials= (double*)((char*)d_ws + 128 + (size_t)8*T);

  int total_cells = B * NA * GG;            // 6,291,456
  int total_quads = total_cells / 4;        // 1,572,864
  int nblk3 = (total_quads + 255) / 256;    // 6144
  int nblkT = (T + 255) / 256;              // 16

  k_targets<<<nblkT, 256, 0, stream>>>(targets, T, G, stride, ocell, keyarr, sums);
  k_sparse <<<nblkT, 256, 0, stream>>>(x, targets, T, G, stride, ocell, keyarr, sums);
  k_dense  <<<nblk3, 256, 0, stream>>>(x, out, partials, G, stride, total_quads);
  k_final  <<<1, 256, 0, stream>>>(sums, partials, nblk3, out + (size_t)total_cells*5, (double)total_cells);
}

// Round 2
// 540.850 us; speedup vs baseline: 1.0607x; 1.0607x over previous
//
#include <hip/hip_runtime.h>
#include <cmath>

#define NA 3
#define HSIZE 8192
#define HMASK (HSIZE - 1)

typedef float v4f __attribute__((ext_vector_type(4)));

// ws layout:
//   0:      double sums[16]     [0]=nb_dense [1]=conf_dense [2]=c50_dense
//                               [3]=excl_nb [4]=excl_conf [5]=excl_cnt
//                               [6..9]=lx,ly,lw,lh [10]=bce_obj [11]=conf_obj
//                               [12]=i50det [13]=i75det [14]=n_obj
//   128:    int A_key[8192]     ownership table, key=okey+1
//   +32768: int A_val[8192]     atomicMax(t+1)  -> last target wins
//   +32768: int B_key[8192]     exclusion table, key=cell+1
//   +32768: int B_bits[8192]    atomicOr(anchor bits)
//   +32768: int B_maxt[8192]    atomicMax(t+1)  -> representative
//   163968: int ocell[T]
//   +4T:    int keyarr[T]

__device__ __forceinline__ float sigf(float v){ return 1.0f/(1.0f + expf(-v)); }
__device__ __forceinline__ unsigned hslot(unsigned key){
  return (key * 2654435761u) >> 19;   // top 13 bits -> [0, 8192)
}

__global__ __launch_bounds__(256) void k_zero(int* __restrict__ p, int n){
  int i = blockIdx.x*256 + threadIdx.x;
  if (i < n) p[i] = 0;
}

__global__ __launch_bounds__(256) void k_targets(
    const float* __restrict__ targets, int T, int G, float stride,
    int* __restrict__ ocell, int* __restrict__ keyarr,
    int* __restrict__ A_key, int* __restrict__ A_val,
    int* __restrict__ B_key, int* __restrict__ B_bits, int* __restrict__ B_maxt)
{
  int t = blockIdx.x*256 + threadIdx.x;
  if (t >= T) return;
  const float* tr = targets + (size_t)t*6;
  int b = (int)tr[0];
  float gx = tr[2]*(float)G, gy = tr[3]*(float)G, gw = tr[4]*(float)G, gh = tr[5]*(float)G;
  float aw[NA] = {116.0f/stride, 156.0f/stride, 373.0f/stride};
  float ah[NA] = { 90.0f/stride, 198.0f/stride, 326.0f/stride};
  float best_iou = -1.0f; int best = 0; int bits = 0;
  #pragma unroll
  for (int a = 0; a < NA; ++a){
    float inter = fminf(aw[a], gw) * fminf(ah[a], gh);
    float uni   = aw[a]*ah[a] + gw*gh - inter;
    float iou   = inter / (uni + 1e-16f);
    if (iou > best_iou){ best_iou = iou; best = a; }
    if (iou > 0.5f) bits |= (1 << a);
  }
  bits |= (1 << best);
  int gi = (int)floorf(gx); gi = gi < 0 ? 0 : (gi > G-1 ? G-1 : gi);
  int gj = (int)floorf(gy); gj = gj < 0 ? 0 : (gj > G-1 ? G-1 : gj);
  int cell = (b*G + gj)*G + gi;             // < 2^21
  int okey = cell*4 + best;
  ocell[t]  = okey;
  keyarr[t] = (cell << 3) | bits;

  // table A: (cell,best) -> max t (last target wins scatter semantics)
  unsigned s = hslot((unsigned)okey) & HMASK;
  for (;;){
    int prev = atomicCAS(&A_key[s], 0, okey+1);
    if (prev == 0 || prev == okey+1){ atomicMax(&A_val[s], t+1); break; }
    s = (s+1) & HMASK;
  }
  // table B: cell -> union of excluded anchor bits, representative = max t
  s = hslot((unsigned)cell) & HMASK;
  for (;;){
    int prev = atomicCAS(&B_key[s], 0, cell+1);
    if (prev == 0 || prev == cell+1){
      atomicOr(&B_bits[s], bits);
      atomicMax(&B_maxt[s], t+1);
      break;
    }
    s = (s+1) & HMASK;
  }
}

__global__ __launch_bounds__(256) void k_sparse(
    const float* __restrict__ x, const float* __restrict__ targets,
    int T, int G, float stride,
    const int* __restrict__ ocell, const int* __restrict__ keyarr,
    const int* __restrict__ A_key, const int* __restrict__ A_val,
    const int* __restrict__ B_key, const int* __restrict__ B_bits,
    const int* __restrict__ B_maxt, double* __restrict__ sums)
{
  int tid = threadIdx.x;
  int t = blockIdx.x*256 + tid;
  double v[12];
  #pragma unroll
  for (int k = 0; k < 12; ++k) v[k] = 0.0;
  // v: [0]=excl_nb [1]=excl_conf [2]=excl_cnt [3..6]=lx,ly,lw,lh
  //    [7]=bce [8]=conf_obj [9]=i50 [10]=i75 [11]=n_obj

  if (t < T){
    const float* tr = targets + (size_t)t*6;
    int b = (int)tr[0];
    float gx = tr[2]*(float)G, gy = tr[3]*(float)G, gw = tr[4]*(float)G, gh = tr[5]*(float)G;
    float aw[NA] = {116.0f/stride, 156.0f/stride, 373.0f/stride};
    float ah[NA] = { 90.0f/stride, 198.0f/stride, 326.0f/stride};
    int okey = ocell[t];
    int myk  = keyarr[t];
    int cell = myk >> 3;
    int best = okey & 3;
    int gi = cell % G;
    int gj = (cell / G) % G;
    int GG = G*G;

    // ownership lookup (last target wins)
    unsigned s = hslot((unsigned)okey) & HMASK;
    while (A_key[s] != okey+1) s = (s+1) & HMASK;
    bool owner = (A_val[s] == t+1);

    if (owner){
      float awb = aw[best], ahb = ah[best];
      const float* xp = x + ((size_t)(b*(NA*5) + best*5))*GG + (size_t)gj*G + gi;
      float x0 = xp[0], x1 = xp[(size_t)GG], x2 = xp[(size_t)2*GG],
            x3 = xp[(size_t)3*GG], x4 = xp[(size_t)4*GG];
      float cx = sigf(x0), cy = sigf(x1), w = x2, h = x3, conf = sigf(x4);
      float tx = gx - (float)gi, ty = gy - (float)gj;
      float tw = logf(gw/awb + 1e-16f), th = logf(gh/ahb + 1e-16f);
      v[3] = (double)((cx-tx)*(cx-tx));
      v[4] = (double)((cy-ty)*(cy-ty));
      v[5] = (double)((w-tw)*(w-tw));
      v[6] = (double)((h-th)*(h-th));
      v[7] = (double)(-logf(conf + 1e-12f));
      v[8] = (double)conf;
      float px = (float)gi + cx, py = (float)gj + cy;
      float pw = expf(w)*awb, ph = expf(h)*ahb;
      float iw = fminf(px + pw*0.5f, gx + gw*0.5f) - fmaxf(px - pw*0.5f, gx - gw*0.5f);
      float ih = fminf(py + ph*0.5f, gy + gh*0.5f) - fmaxf(py - ph*0.5f, gy - gh*0.5f);
      iw = fmaxf(iw, 0.0f); ih = fmaxf(ih, 0.0f);
      float inter = iw*ih;
      float iou = inter / (pw*ph + gw*gh - inter + 1e-16f);
      bool det = conf > 0.5f;
      v[9]  = (iou > 0.5f  && det) ? 1.0 : 0.0;
      v[10] = (iou > 0.75f && det) ? 1.0 : 0.0;
      v[11] = 1.0;
    }

    // exclusion: representative per distinct cell processes the bit union
    s = hslot((unsigned)cell) & HMASK;
    while (B_key[s] != cell+1) s = (s+1) & HMASK;
    if (B_maxt[s] == t+1){
      int bits = B_bits[s];
      #pragma unroll
      for (int a = 0; a < NA; ++a){
        if (bits & (1 << a)){
          float x4 = x[((size_t)(b*(NA*5) + a*5 + 4))*GG + (size_t)gj*G + gi];
          float conf = sigf(x4);
          v[0] += (double)(-logf(1.0f - conf + 1e-12f));
          v[1] += (double)conf;
          v[2] += 1.0;
        }
      }
    }
  }

  // wave shuffle reduce, then 4 wave-partials in LDS, then atomics
  #pragma unroll
  for (int k = 0; k < 12; ++k){
    #pragma unroll
    for (int off = 32; off > 0; off >>= 1) v[k] += __shfl_down(v[k], off);
  }
  __shared__ double sred[4][12];
  int lane = tid & 63, wv = tid >> 6;
  if (lane == 0){
    #pragma unroll
    for (int k = 0; k < 12; ++k) sred[wv][k] = v[k];
  }
  __syncthreads();
  if (tid < 12){
    double sm = sred[0][tid] + sred[1][tid] + sred[2][tid] + sred[3][tid];
    unsafeAtomicAdd(&sums[3 + tid], sm);
  }
}

__global__ __launch_bounds__(256) void k_dense(
    const float* __restrict__ x, float* __restrict__ out,
    double* __restrict__ sums, int G, float stride, int total_cells)
{
  int i = blockIdx.x*256 + threadIdx.x;
  int cell = i*8;
  double nb = 0.0, cs = 0.0;
  int c50i = 0;
  if (cell < total_cells){
    int GG = G*G;
    int gx    = cell % G;           // multiple of 8
    int row   = cell / G;
    int gy    = row % G;
    int plane = row / G;            // b*3 + a
    int a     = plane % NA;
    float aw_all[NA] = {116.0f/stride, 156.0f/stride, 373.0f/stride};
    float ah_all[NA] = { 90.0f/stride, 198.0f/stride, 326.0f/stride};
    float aw = aw_all[a], ah = ah_all[a];

    size_t base = (size_t)plane*5*GG + (size_t)gy*G + gx;
    v4f v[5][2];
    #pragma unroll
    for (int c = 0; c < 5; ++c){
      const v4f* p = (const v4f*)(x + base + (size_t)c*GG);
      v[c][0] = __builtin_nontemporal_load(p);
      v[c][1] = __builtin_nontemporal_load(p + 1);
    }

    float o[40];
    #pragma unroll
    for (int j = 0; j < 8; ++j){
      float p0 = v[0][j>>2][j&3];
      float p1 = v[1][j>>2][j&3];
      float p2 = v[2][j>>2][j&3];
      float p3 = v[3][j>>2][j&3];
      float p4 = v[4][j>>2][j&3];
      float cx   = 1.0f/(1.0f + expf(-p0));
      float cy   = 1.0f/(1.0f + expf(-p1));
      float pw   = expf(p2)*aw;
      float ph   = expf(p3)*ah;
      float conf = 1.0f/(1.0f + expf(-p4));
      o[j*5+0] = ((float)(gx + j) + cx)*stride;
      o[j*5+1] = ((float)gy + cy)*stride;
      o[j*5+2] = pw*stride;
      o[j*5+3] = ph*stride;
      o[j*5+4] = conf;
      nb += (double)(-logf(1.0f - conf + 1e-12f));
      cs += (double)conf;
      c50i += (conf > 0.5f) ? 1 : 0;
    }
    v4f* od = (v4f*)(out + (size_t)cell*5);  // cell%8==0 -> 160B offset, 16B aligned
    const v4f* ov = (const v4f*)o;
    #pragma unroll
    for (int j = 0; j < 10; ++j) __builtin_nontemporal_store(ov[j], od + j);
  }

  double vals[3] = {nb, cs, (double)c50i};
  #pragma unroll
  for (int k = 0; k < 3; ++k){
    #pragma unroll
    for (int off = 32; off > 0; off >>= 1) vals[k] += __shfl_down(vals[k], off);
  }
  __shared__ double sred[4][3];
  int lane = threadIdx.x & 63, wv = threadIdx.x >> 6;
  if (lane == 0){
    sred[wv][0] = vals[0]; sred[wv][1] = vals[1]; sred[wv][2] = vals[2];
  }
  __syncthreads();
  if (threadIdx.x < 3){
    double sm = sred[0][threadIdx.x] + sred[1][threadIdx.x]
              + sred[2][threadIdx.x] + sred[3][threadIdx.x];
    unsafeAtomicAdd(&sums[threadIdx.x], sm);
  }
}

__global__ __launch_bounds__(64) void k_final(
    const double* __restrict__ sums, float* __restrict__ tail, double total_cells)
{
  if (threadIdx.x != 0) return;
  double nb_all = sums[0], conf_all = sums[1], c50_all = sums[2];
  double enb = sums[3], econf = sums[4], ecnt = sums[5];
  double lx = sums[6], ly = sums[7], lw = sums[8], lh = sums[9];
  double bce = sums[10], cobj = sums[11], i50 = sums[12], i75 = sums[13], nobj = sums[14];

  double dObj = fmax(nobj, 1.0);
  double n_noobj = total_cells - ecnt;
  double dNo  = fmax(n_noobj, 1.0);

  double loss_x = lx/dObj, loss_y = ly/dObj, loss_w = lw/dObj, loss_h = lh/dObj;
  double loss_bbox = loss_x + loss_y + loss_w + loss_h;
  double loss_conf_obj   = bce/dObj;
  double loss_conf_noobj = (nb_all - enb)/dNo;
  double loss_conf  = 100.0*loss_conf_obj + 1.0*loss_conf_noobj;
  double loss_layer = loss_bbox + loss_conf;
  double conf_obj   = cobj/dObj;
  double conf_noobj = (conf_all - econf)/dNo;
  double precision  = i50/(c50_all + 1e-16);
  double recall50   = i50/(nobj + 1e-16);
  double recall75   = i75/(nobj + 1e-16);

  tail[0]  = (float)loss_layer;
  tail[1]  = (float)loss_x;
  tail[2]  = (float)loss_y;
  tail[3]  = (float)loss_w;
  tail[4]  = (float)loss_h;
  tail[5]  = (float)loss_bbox;
  tail[6]  = (float)loss_conf;
  tail[7]  = (float)loss_layer;
  tail[8]  = (float)conf_obj;
  tail[9]  = (float)conf_noobj;
  tail[10] = (float)precision;
  tail[11] = (float)recall50;
  tail[12] = (float)recall75;
}

extern "C" void kernel_launch(void* const* d_in, const int* in_sizes, int n_in,
                              void* d_out, int out_size, void* d_ws, size_t ws_size,
                              hipStream_t stream) {
  const float* x       = (const float*)d_in[0];
  const float* targets = (const float*)d_in[1];
  float* out = (float*)d_out;

  const int B = 32;
  int GG = in_sizes[0] / (B * NA * 5);
  int G = (int)(sqrt((double)GG) + 0.5);
  int T = in_sizes[1] / 6;
  float stride = 2048.0f / (float)G;

  char* ws = (char*)d_ws;
  double* sums  = (double*)ws;
  int* A_key  = (int*)(ws + 128);
  int* A_val  = A_key + HSIZE;
  int* B_key  = A_val + HSIZE;
  int* B_bits = B_key + HSIZE;
  int* B_maxt = B_bits + HSIZE;
  int* ocell  = B_maxt + HSIZE;
  int* keyarr = ocell + T;

  int total_cells = B * NA * GG;            // 6,291,456
  int nzero = 32 + 5*HSIZE;                 // sums (as ints) + tables
  int nblkZ = (nzero + 255) / 256;
  int nblkT = (T + 255) / 256;
  int nblkD = (total_cells/8 + 255) / 256;  // 3072

  k_zero   <<<nblkZ, 256, 0, stream>>>((int*)ws, nzero);
  k_targets<<<nblkT, 256, 0, stream>>>(targets, T, G, stride, ocell, keyarr,
                                       A_key, A_val, B_key, B_bits, B_maxt);
  k_sparse <<<nblkT, 256, 0, stream>>>(x, targets, T, G, stride, ocell, keyarr,
                                       A_key, A_val, B_key, B_bits, B_maxt, sums);
  k_dense  <<<nblkD, 256, 0, stream>>>(x, out, sums, G, stride, total_cells);
  k_final  <<<1, 64, 0, stream>>>(sums, out + (size_t)total_cells*5, (double)total_cells);
}

// Round 3
// 258.928 us; speedup vs baseline: 2.2156x; 2.0888x over previous
//
#include <hip/hip_runtime.h>
#include <cmath>

#define NA 3
#define HSIZE 8192
#define HMASK (HSIZE - 1)

typedef float v4f __attribute__((ext_vector_type(4)));

// ws layout:
//   0:      double sums[16]     [0]=nb_dense [1]=conf_dense [2]=c50_dense
//                               [3]=excl_nb [4]=excl_conf [5]=excl_cnt
//                               [6..9]=lx,ly,lw,lh [10]=bce_obj [11]=conf_obj
//                               [12]=i50det [13]=i75det [14]=n_obj
//   128:    int A_key[8192]  A_val[8192]  B_key[8192]  B_bits[8192]  B_maxt[8192]
//   then:   int ocell[T]  keyarr[T]

__device__ __forceinline__ float sigf(float v){ return 1.0f/(1.0f + expf(-v)); }
__device__ __forceinline__ unsigned hslot(unsigned key){
  return (key * 2654435761u) >> 19;   // top 13 bits -> [0, 8192)
}

__global__ __launch_bounds__(256) void k_zero(int* __restrict__ p, int n){
  int i = blockIdx.x*256 + threadIdx.x;
  if (i < n) p[i] = 0;
}

__global__ __launch_bounds__(256) void k_targets(
    const float* __restrict__ targets, int T, int G, float stride,
    int* __restrict__ ocell, int* __restrict__ keyarr,
    int* __restrict__ A_key, int* __restrict__ A_val,
    int* __restrict__ B_key, int* __restrict__ B_bits, int* __restrict__ B_maxt)
{
  int t = blockIdx.x*256 + threadIdx.x;
  if (t >= T) return;
  const float* tr = targets + (size_t)t*6;
  int b = (int)tr[0];
  float gx = tr[2]*(float)G, gy = tr[3]*(float)G, gw = tr[4]*(float)G, gh = tr[5]*(float)G;
  float aw[NA] = {116.0f/stride, 156.0f/stride, 373.0f/stride};
  float ah[NA] = { 90.0f/stride, 198.0f/stride, 326.0f/stride};
  float best_iou = -1.0f; int best = 0; int bits = 0;
  #pragma unroll
  for (int a = 0; a < NA; ++a){
    float inter = fminf(aw[a], gw) * fminf(ah[a], gh);
    float uni   = aw[a]*ah[a] + gw*gh - inter;
    float iou   = inter / (uni + 1e-16f);
    if (iou > best_iou){ best_iou = iou; best = a; }
    if (iou > 0.5f) bits |= (1 << a);
  }
  bits |= (1 << best);
  int gi = (int)floorf(gx); gi = gi < 0 ? 0 : (gi > G-1 ? G-1 : gi);
  int gj = (int)floorf(gy); gj = gj < 0 ? 0 : (gj > G-1 ? G-1 : gj);
  int cell = (b*G + gj)*G + gi;             // < 2^21
  int okey = cell*4 + best;
  ocell[t]  = okey;
  keyarr[t] = (cell << 3) | bits;

  // table A: (cell,best) -> max t (last target wins scatter semantics)
  unsigned s = hslot((unsigned)okey) & HMASK;
  for (;;){
    int prev = atomicCAS(&A_key[s], 0, okey+1);
    if (prev == 0 || prev == okey+1){ atomicMax(&A_val[s], t+1); break; }
    s = (s+1) & HMASK;
  }
  // table B: cell -> union of excluded anchor bits, representative = max t
  s = hslot((unsigned)cell) & HMASK;
  for (;;){
    int prev = atomicCAS(&B_key[s], 0, cell+1);
    if (prev == 0 || prev == cell+1){
      atomicOr(&B_bits[s], bits);
      atomicMax(&B_maxt[s], t+1);
      break;
    }
    s = (s+1) & HMASK;
  }
}

__global__ __launch_bounds__(256) void k_sparse(
    const float* __restrict__ x, const float* __restrict__ targets,
    int T, int G, float stride,
    const int* __restrict__ ocell, const int* __restrict__ keyarr,
    const int* __restrict__ A_key, const int* __restrict__ A_val,
    const int* __restrict__ B_key, const int* __restrict__ B_bits,
    const int* __restrict__ B_maxt, double* __restrict__ sums)
{
  int tid = threadIdx.x;
  int t = blockIdx.x*256 + tid;
  double v[12];
  #pragma unroll
  for (int k = 0; k < 12; ++k) v[k] = 0.0;
  // v: [0]=excl_nb [1]=excl_conf [2]=excl_cnt [3..6]=lx,ly,lw,lh
  //    [7]=bce [8]=conf_obj [9]=i50 [10]=i75 [11]=n_obj

  if (t < T){
    const float* tr = targets + (size_t)t*6;
    int b = (int)tr[0];
    float gx = tr[2]*(float)G, gy = tr[3]*(float)G, gw = tr[4]*(float)G, gh = tr[5]*(float)G;
    float aw[NA] = {116.0f/stride, 156.0f/stride, 373.0f/stride};
    float ah[NA] = { 90.0f/stride, 198.0f/stride, 326.0f/stride};
    int okey = ocell[t];
    int myk  = keyarr[t];
    int cell = myk >> 3;
    int best = okey & 3;
    int gi = cell % G;
    int gj = (cell / G) % G;
    int GG = G*G;

    // ownership lookup (last target wins)
    unsigned s = hslot((unsigned)okey) & HMASK;
    while (A_key[s] != okey+1) s = (s+1) & HMASK;
    bool owner = (A_val[s] == t+1);

    if (owner){
      float awb = aw[best], ahb = ah[best];
      const float* xp = x + ((size_t)(b*(NA*5) + best*5))*GG + (size_t)gj*G + gi;
      float x0 = xp[0], x1 = xp[(size_t)GG], x2 = xp[(size_t)2*GG],
            x3 = xp[(size_t)3*GG], x4 = xp[(size_t)4*GG];
      float cx = sigf(x0), cy = sigf(x1), w = x2, h = x3, conf = sigf(x4);
      float tx = gx - (float)gi, ty = gy - (float)gj;
      float tw = logf(gw/awb + 1e-16f), th = logf(gh/ahb + 1e-16f);
      v[3] = (double)((cx-tx)*(cx-tx));
      v[4] = (double)((cy-ty)*(cy-ty));
      v[5] = (double)((w-tw)*(w-tw));
      v[6] = (double)((h-th)*(h-th));
      v[7] = (double)(-logf(conf + 1e-12f));
      v[8] = (double)conf;
      float px = (float)gi + cx, py = (float)gj + cy;
      float pw = expf(w)*awb, ph = expf(h)*ahb;
      float iw = fminf(px + pw*0.5f, gx + gw*0.5f) - fmaxf(px - pw*0.5f, gx - gw*0.5f);
      float ih = fminf(py + ph*0.5f, gy + gh*0.5f) - fmaxf(py - ph*0.5f, gy - gh*0.5f);
      iw = fmaxf(iw, 0.0f); ih = fmaxf(ih, 0.0f);
      float inter = iw*ih;
      float iou = inter / (pw*ph + gw*gh - inter + 1e-16f);
      bool det = conf > 0.5f;
      v[9]  = (iou > 0.5f  && det) ? 1.0 : 0.0;
      v[10] = (iou > 0.75f && det) ? 1.0 : 0.0;
      v[11] = 1.0;
    }

    // exclusion: representative per distinct cell processes the bit union
    s = hslot((unsigned)cell) & HMASK;
    while (B_key[s] != cell+1) s = (s+1) & HMASK;
    if (B_maxt[s] == t+1){
      int bits = B_bits[s];
      #pragma unroll
      for (int a = 0; a < NA; ++a){
        if (bits & (1 << a)){
          float x4 = x[((size_t)(b*(NA*5) + a*5 + 4))*GG + (size_t)gj*G + gi];
          float conf = sigf(x4);
          v[0] += (double)(-logf(1.0f - conf + 1e-12f));
          v[1] += (double)conf;
          v[2] += 1.0;
        }
      }
    }
  }

  // wave shuffle reduce, then 4 wave-partials in LDS, then atomics
  #pragma unroll
  for (int k = 0; k < 12; ++k){
    #pragma unroll
    for (int off = 32; off > 0; off >>= 1) v[k] += __shfl_down(v[k], off);
  }
  __shared__ double sred[4][12];
  int lane = tid & 63, wv = tid >> 6;
  if (lane == 0){
    #pragma unroll
    for (int k = 0; k < 12; ++k) sred[wv][k] = v[k];
  }
  __syncthreads();
  if (tid < 12){
    double sm = sred[0][tid] + sred[1][tid] + sred[2][tid] + sred[3][tid];
    unsafeAtomicAdd(&sums[3 + tid], sm);
  }
}

// 8 cells/thread. Planar coalesced loads -> compute -> LDS (stride-41 floats,
// conflict-free) -> per-wave fully coalesced 1KB nontemporal stores.
__global__ __launch_bounds__(256) void k_dense(
    const float* __restrict__ x, float* __restrict__ out,
    double* __restrict__ sums, int G, float stride, int total_cells)
{
  __shared__ float lds[256*41];   // 41,984 B
  int tid = threadIdx.x;
  int i = blockIdx.x*256 + tid;
  int cell = i*8;
  double nb = 0.0, cs = 0.0;
  int c50i = 0;

  if (cell < total_cells){
    int GG = G*G;
    int gx    = cell % G;           // multiple of 8
    int row   = cell / G;
    int gy    = row % G;
    int plane = row / G;            // b*3 + a
    int a     = plane % NA;
    float aw_all[NA] = {116.0f/stride, 156.0f/stride, 373.0f/stride};
    float ah_all[NA] = { 90.0f/stride, 198.0f/stride, 326.0f/stride};
    float aw = aw_all[a], ah = ah_all[a];

    size_t base = (size_t)plane*5*GG + (size_t)gy*G + gx;
    v4f v[5][2];
    #pragma unroll
    for (int c = 0; c < 5; ++c){
      const v4f* p = (const v4f*)(x + base + (size_t)c*GG);
      v[c][0] = p[0];
      v[c][1] = p[1];
    }

    float* myl = lds + tid*41;
    #pragma unroll
    for (int j = 0; j < 8; ++j){
      float p0 = v[0][j>>2][j&3];
      float p1 = v[1][j>>2][j&3];
      float p2 = v[2][j>>2][j&3];
      float p3 = v[3][j>>2][j&3];
      float p4 = v[4][j>>2][j&3];
      float cx   = 1.0f/(1.0f + expf(-p0));
      float cy   = 1.0f/(1.0f + expf(-p1));
      float pw   = expf(p2)*aw;
      float ph   = expf(p3)*ah;
      float conf = 1.0f/(1.0f + expf(-p4));
      myl[j*5+0] = ((float)(gx + j) + cx)*stride;
      myl[j*5+1] = ((float)gy + cy)*stride;
      myl[j*5+2] = pw*stride;
      myl[j*5+3] = ph*stride;
      myl[j*5+4] = conf;
      nb += (double)(-logf(1.0f - conf + 1e-12f));
      cs += (double)conf;
      c50i += (conf > 0.5f) ? 1 : 0;
    }
  }
  __syncthreads();

  // store phase: wave wv owns output floats [waveBase, waveBase+2560)
  int lane = tid & 63, wv = tid >> 6;
  {
    size_t waveBase = ((size_t)blockIdx.x*2048 + (size_t)wv*512)*5;
    if (waveBase < (size_t)total_cells*5){
      const float* wl = lds + (size_t)(wv*64)*41;
      #pragma unroll
      for (int c = 0; c < 10; ++c){
        int f = (c*64 + lane)*4;        // [0, 2560)
        int owner = f / 40;
        int within = f - owner*40;
        const float* src = wl + owner*41 + within;
        v4f val;
        val.x = src[0]; val.y = src[1]; val.z = src[2]; val.w = src[3];
        __builtin_nontemporal_store(val, (v4f*)(out + waveBase + f));
      }
    }
  }

  double vals[3] = {nb, cs, (double)c50i};
  #pragma unroll
  for (int k = 0; k < 3; ++k){
    #pragma unroll
    for (int off = 32; off > 0; off >>= 1) vals[k] += __shfl_down(vals[k], off);
  }
  __shared__ double sred[4][3];
  if (lane == 0){
    sred[wv][0] = vals[0]; sred[wv][1] = vals[1]; sred[wv][2] = vals[2];
  }
  __syncthreads();
  if (tid < 3){
    double sm = sred[0][tid] + sred[1][tid] + sred[2][tid] + sred[3][tid];
    unsafeAtomicAdd(&sums[tid], sm);
  }
}

__global__ __launch_bounds__(64) void k_final(
    const double* __restrict__ sums, float* __restrict__ tail, double total_cells)
{
  if (threadIdx.x != 0) return;
  double nb_all = sums[0], conf_all = sums[1], c50_all = sums[2];
  double enb = sums[3], econf = sums[4], ecnt = sums[5];
  double lx = sums[6], ly = sums[7], lw = sums[8], lh = sums[9];
  double bce = sums[10], cobj = sums[11], i50 = sums[12], i75 = sums[13], nobj = sums[14];

  double dObj = fmax(nobj, 1.0);
  double n_noobj = total_cells - ecnt;
  double dNo  = fmax(n_noobj, 1.0);

  double loss_x = lx/dObj, loss_y = ly/dObj, loss_w = lw/dObj, loss_h = lh/dObj;
  double loss_bbox = loss_x + loss_y + loss_w + loss_h;
  double loss_conf_obj   = bce/dObj;
  double loss_conf_noobj = (nb_all - enb)/dNo;
  double loss_conf  = 100.0*loss_conf_obj + 1.0*loss_conf_noobj;
  double loss_layer = loss_bbox + loss_conf;
  double conf_obj   = cobj/dObj;
  double conf_noobj = (conf_all - econf)/dNo;
  double precision  = i50/(c50_all + 1e-16);
  double recall50   = i50/(nobj + 1e-16);
  double recall75   = i75/(nobj + 1e-16);

  tail[0]  = (float)loss_layer;
  tail[1]  = (float)loss_x;
  tail[2]  = (float)loss_y;
  tail[3]  = (float)loss_w;
  tail[4]  = (float)loss_h;
  tail[5]  = (float)loss_bbox;
  tail[6]  = (float)loss_conf;
  tail[7]  = (float)loss_layer;
  tail[8]  = (float)conf_obj;
  tail[9]  = (float)conf_noobj;
  tail[10] = (float)precision;
  tail[11] = (float)recall50;
  tail[12] = (float)recall75;
}

extern "C" void kernel_launch(void* const* d_in, const int* in_sizes, int n_in,
                              void* d_out, int out_size, void* d_ws, size_t ws_size,
                              hipStream_t stream) {
  const float* x       = (const float*)d_in[0];
  const float* targets = (const float*)d_in[1];
  float* out = (float*)d_out;

  const int B = 32;
  int GG = in_sizes[0] / (B * NA * 5);
  int G = (int)(sqrt((double)GG) + 0.5);
  int T = in_sizes[1] / 6;
  float stride = 2048.0f / (float)G;

  char* ws = (char*)d_ws;
  double* sums  = (double*)ws;
  int* A_key  = (int*)(ws + 128);
  int* A_val  = A_key + HSIZE;
  int* B_key  = A_val + HSIZE;
  int* B_bits = B_key + HSIZE;
  int* B_maxt = B_bits + HSIZE;
  int* ocell  = B_maxt + HSIZE;
  int* keyarr = ocell + T;

  int total_cells = B * NA * GG;            // 6,291,456
  int nzero = 32 + 5*HSIZE;                 // sums (as ints) + tables
  int nblkZ = (nzero + 255) / 256;
  int nblkT = (T + 255) / 256;
  int nblkD = (total_cells/8 + 255) / 256;  // 3072

  k_zero   <<<nblkZ, 256, 0, stream>>>((int*)ws, nzero);
  k_targets<<<nblkT, 256, 0, stream>>>(targets, T, G, stride, ocell, keyarr,
                                       A_key, A_val, B_key, B_bits, B_maxt);
  k_sparse <<<nblkT, 256, 0, stream>>>(x, targets, T, G, stride, ocell, keyarr,
                                       A_key, A_val, B_key, B_bits, B_maxt, sums);
  k_dense  <<<nblkD, 256, 0, stream>>>(x, out, sums, G, stride, total_cells);
  k_final  <<<1, 64, 0, stream>>>(sums, out + (size_t)total_cells*5, (double)total_cells);
}